// Round 1
// baseline (75.097 us; speedup 1.0000x reference)
//
#include <hip/hip_runtime.h>
#include <math.h>

// Quanvolution hybrid quantum forward — collapsed.
// Key observation: the attention stage only reads features[:, :4], which is
// patch 0 of the quanvolution (pixels at flat offsets 0,1,28,29 of each 28x28
// image). Everything else in the 196-patch filter is dead code w.r.t. the
// (B,10) log_softmax output. So: one thread per batch element, 16-complex-amp
// 4-qubit statevector entirely in registers.

#define DEVFN static __device__ __forceinline__

// wire w uses bit (3-w) of the 4-bit amplitude index (tq convention: wire 0
// is the most significant axis).

// KIND: 0=ry, 1=rx, 2=rz. half = theta*0.5
template <int WIRE, int KIND>
DEVFN void rot(float* re, float* im, float half) {
    const float c = __cosf(half) * 0.0f + cosf(half);  // keep precise cosf
    const float s = sinf(half);
    constexpr int bit = 1 << (3 - WIRE);
#pragma unroll
    for (int i = 0; i < 16; ++i) {
        if (i & bit) continue;
        const int j = i | bit;
        const float r0 = re[i], i0 = im[i];
        const float r1 = re[j], i1 = im[j];
        if (KIND == 0) {  // RY: n0 = c*s0 - s*s1 ; n1 = s*s0 + c*s1
            re[i] = c * r0 - s * r1;  im[i] = c * i0 - s * i1;
            re[j] = s * r0 + c * r1;  im[j] = s * i0 + c * i1;
        } else if (KIND == 1) {  // RX: n0 = c*s0 - i*s*s1 ; n1 = -i*s*s0 + c*s1
            re[i] = c * r0 + s * i1;  im[i] = c * i0 - s * r1;
            re[j] = c * r1 + s * i0;  im[j] = c * i1 - s * r0;
        } else {  // RZ: n0 = (c - i*s)*s0 ; n1 = (c + i*s)*s1
            re[i] = c * r0 + s * i0;  im[i] = c * i0 - s * r0;
            re[j] = c * r1 - s * i1;  im[j] = c * i1 + s * r1;
        }
    }
}

template <int C, int T>
DEVFN void cnot(float* re, float* im) {
    constexpr int cb = 1 << (3 - C);
    constexpr int tb = 1 << (3 - T);
#pragma unroll
    for (int i = 0; i < 16; ++i) {
        if ((i & cb) && !(i & tb)) {
            const int j = i | tb;
            const float tr = re[i], ti = im[i];
            re[i] = re[j]; im[i] = im[j];
            re[j] = tr;    im[j] = ti;
        }
    }
}

template <int WIRE>
DEVFN float measZ(const float* re, const float* im) {
    constexpr int bit = 1 << (3 - WIRE);
    float acc = 0.0f;
#pragma unroll
    for (int i = 0; i < 16; ++i) {
        const float p = re[i] * re[i] + im[i] * im[i];
        acc += (i & bit) ? -p : p;
    }
    return acc;
}

DEVFN void init_state(float* re, float* im) {
#pragma unroll
    for (int i = 0; i < 16; ++i) { re[i] = 0.0f; im[i] = 0.0f; }
    re[0] = 1.0f;
}

DEVFN void encode_ry(float* re, float* im, float a0, float a1, float a2, float a3) {
    rot<0, 0>(re, im, a0 * 0.5f);
    rot<1, 0>(re, im, a1 * 0.5f);
    rot<2, 0>(re, im, a2 * 0.5f);
    rot<3, 0>(re, im, a3 * 0.5f);
}

// RL_OPS = [ry0, rx1, rz2, cnot(0,1), ry3, cnot(2,3), rx0, cnot(1,2)]
DEVFN void random_layer(float* re, float* im,
                        float p0, float p1, float p2, float p3, float p4) {
    rot<0, 0>(re, im, p0 * 0.5f);   // ry wire 0
    rot<1, 1>(re, im, p1 * 0.5f);   // rx wire 1
    rot<2, 2>(re, im, p2 * 0.5f);   // rz wire 2
    cnot<0, 1>(re, im);
    rot<3, 0>(re, im, p3 * 0.5f);   // ry wire 3
    cnot<2, 3>(re, im);
    rot<0, 1>(re, im, p4 * 0.5f);   // rx wire 0
    cnot<1, 2>(re, im);
}

__global__ void __launch_bounds__(256)
quanv_collapsed_kernel(const float* __restrict__ x,
                       const float* __restrict__ fp,
                       const float* __restrict__ ap,
                       const float* __restrict__ kp,
                       const float* __restrict__ W,   // (10,5) row-major
                       const float* __restrict__ bia, // (10,)
                       float* __restrict__ out,       // (B,10)
                       int B) {
    const int t = blockIdx.x * blockDim.x + threadIdx.x;
    if (t >= B) return;

    // patch 0 of image t: flat offsets 0, 1, 28, 29
    const float* img = x + (size_t)t * 784;
    const float a0 = img[0];
    const float a1 = img[1];
    const float a2 = img[28];
    const float a3 = img[29];

    const float f0 = fp[0], f1 = fp[1], f2 = fp[2], f3 = fp[3], f4 = fp[4];
    const float q0 = ap[0], q1 = ap[1], q2 = ap[2], q3 = ap[3], q4 = ap[4];
    const float k0 = kp[0], k1 = kp[1], k2 = kp[2], k3 = kp[3], k4 = kp[4];

    float re[16], im[16];

    // ---- Stage 1: quantum filter on patch 0 ----
    init_state(re, im);
    encode_ry(re, im, a0, a1, a2, a3);
    random_layer(re, im, f0, f1, f2, f3, f4);
    const float m0 = measZ<0>(re, im);
    const float m1 = measZ<1>(re, im);
    const float m2 = measZ<2>(re, im);
    const float m3 = measZ<3>(re, im);

    // ---- Stage 2: quantum self-attention on the 4 features ----
    init_state(re, im);
    encode_ry(re, im, m0, m1, m2, m3);
    random_layer(re, im, q0, q1, q2, q3, q4);
    const float at0 = measZ<0>(re, im);
    const float at1 = measZ<1>(re, im);
    const float at2 = measZ<2>(re, im);
    const float at3 = measZ<3>(re, im);

    // ---- Stage 3: quantum kernel scalar (data-independent, ~cheap) ----
    init_state(re, im);
    random_layer(re, im, k0, k1, k2, k3, k4);
    random_layer(re, im, k0, k1, k2, k3, k4);
    const float kval = sqrtf(re[0] * re[0] + im[0] * im[0]);

    // ---- Stage 4: linear + log_softmax ----
    float logit[10];
    float mx = -INFINITY;
#pragma unroll
    for (int c = 0; c < 10; ++c) {
        float v = bia[c];
        v += at0 * W[c * 5 + 0];
        v += at1 * W[c * 5 + 1];
        v += at2 * W[c * 5 + 2];
        v += at3 * W[c * 5 + 3];
        v += kval * W[c * 5 + 4];
        logit[c] = v;
        mx = fmaxf(mx, v);
    }
    float sum = 0.0f;
#pragma unroll
    for (int c = 0; c < 10; ++c) sum += expf(logit[c] - mx);
    const float lse = logf(sum) + mx;

    float* o = out + (size_t)t * 10;
#pragma unroll
    for (int c = 0; c < 10; ++c) o[c] = logit[c] - lse;
}

extern "C" void kernel_launch(void* const* d_in, const int* in_sizes, int n_in,
                              void* d_out, int out_size, void* d_ws, size_t ws_size,
                              hipStream_t stream) {
    const float* x  = (const float*)d_in[0];
    const float* fp = (const float*)d_in[1];
    const float* ap = (const float*)d_in[2];
    const float* kp = (const float*)d_in[3];
    const float* W  = (const float*)d_in[4];
    const float* b  = (const float*)d_in[5];
    float* out = (float*)d_out;

    const int B = in_sizes[0] / 784;  // 4096
    const int block = 256;
    const int grid = (B + block - 1) / block;
    quanv_collapsed_kernel<<<grid, block, 0, stream>>>(x, fp, ap, kp, W, b, out, B);
}

// Round 2
// 69.146 us; speedup vs baseline: 1.0861x; 1.0861x over previous
//
#include <hip/hip_runtime.h>
#include <math.h>

// Quanvolution hybrid quantum forward — collapsed.
// The attention stage only reads features[:, :4] = patch 0 of the
// quanvolution (pixels at flat offsets 0,1,28,29 of each 28x28 image).
// All other 195 patches are dead code w.r.t. the (B,10) output.
// One thread per batch element; 16-complex-amp statevector in registers.
// This revision: fast trig (__sincosf -> v_sin/v_cos), float2 pixel loads,
// reused trig for the doubled kernel-ansatz application.

#define DEVFN static __device__ __forceinline__

// wire w uses bit (3-w) of the 4-bit amplitude index (tq convention).

// KIND: 0=ry, 1=rx, 2=rz. c,s = cos/sin of theta/2 (precomputed).
template <int WIRE, int KIND>
DEVFN void rot_cs(float* re, float* im, float c, float s) {
    constexpr int bit = 1 << (3 - WIRE);
#pragma unroll
    for (int i = 0; i < 16; ++i) {
        if (i & bit) continue;
        const int j = i | bit;
        const float r0 = re[i], i0 = im[i];
        const float r1 = re[j], i1 = im[j];
        if (KIND == 0) {  // RY
            re[i] = c * r0 - s * r1;  im[i] = c * i0 - s * i1;
            re[j] = s * r0 + c * r1;  im[j] = s * i0 + c * i1;
        } else if (KIND == 1) {  // RX
            re[i] = c * r0 + s * i1;  im[i] = c * i0 - s * r1;
            re[j] = c * r1 + s * i0;  im[j] = c * i1 - s * r0;
        } else {  // RZ
            re[i] = c * r0 + s * i0;  im[i] = c * i0 - s * r0;
            re[j] = c * r1 - s * i1;  im[j] = c * i1 + s * r1;
        }
    }
}

template <int WIRE, int KIND>
DEVFN void rot(float* re, float* im, float half) {
    float s, c;
    __sincosf(half, &s, &c);
    rot_cs<WIRE, KIND>(re, im, c, s);
}

template <int C, int T>
DEVFN void cnot(float* re, float* im) {
    constexpr int cb = 1 << (3 - C);
    constexpr int tb = 1 << (3 - T);
#pragma unroll
    for (int i = 0; i < 16; ++i) {
        if ((i & cb) && !(i & tb)) {
            const int j = i | tb;
            const float tr = re[i], ti = im[i];
            re[i] = re[j]; im[i] = im[j];
            re[j] = tr;    im[j] = ti;
        }
    }
}

template <int WIRE>
DEVFN float measZ(const float* re, const float* im) {
    constexpr int bit = 1 << (3 - WIRE);
    float acc = 0.0f;
#pragma unroll
    for (int i = 0; i < 16; ++i) {
        const float p = re[i] * re[i] + im[i] * im[i];
        acc += (i & bit) ? -p : p;
    }
    return acc;
}

DEVFN void init_state(float* re, float* im) {
#pragma unroll
    for (int i = 0; i < 16; ++i) { re[i] = 0.0f; im[i] = 0.0f; }
    re[0] = 1.0f;
}

DEVFN void encode_ry(float* re, float* im, float a0, float a1, float a2, float a3) {
    rot<0, 0>(re, im, a0 * 0.5f);
    rot<1, 0>(re, im, a1 * 0.5f);
    rot<2, 0>(re, im, a2 * 0.5f);
    rot<3, 0>(re, im, a3 * 0.5f);
}

// RL_OPS = [ry0, rx1, rz2, cnot(0,1), ry3, cnot(2,3), rx0, cnot(1,2)]
// Takes precomputed (c,s) for the 5 parameterized rotations.
DEVFN void random_layer_cs(float* re, float* im, const float* c, const float* s) {
    rot_cs<0, 0>(re, im, c[0], s[0]);   // ry wire 0
    rot_cs<1, 1>(re, im, c[1], s[1]);   // rx wire 1
    rot_cs<2, 2>(re, im, c[2], s[2]);   // rz wire 2
    cnot<0, 1>(re, im);
    rot_cs<3, 0>(re, im, c[3], s[3]);   // ry wire 3
    cnot<2, 3>(re, im);
    rot_cs<0, 1>(re, im, c[4], s[4]);   // rx wire 0
    cnot<1, 2>(re, im);
}

__global__ void __launch_bounds__(64)
quanv_collapsed_kernel(const float* __restrict__ x,
                       const float* __restrict__ fp,
                       const float* __restrict__ ap,
                       const float* __restrict__ kp,
                       const float* __restrict__ W,   // (10,5) row-major
                       const float* __restrict__ bia, // (10,)
                       float* __restrict__ out,       // (B,10)
                       int B) {
    const int t = blockIdx.x * blockDim.x + threadIdx.x;
    if (t >= B) return;

    // patch 0 of image t: flat float offsets 0,1,28,29 (8B-aligned pairs)
    const float* img = x + (size_t)t * 784;
    const float2 p01 = *reinterpret_cast<const float2*>(img);
    const float2 p23 = *reinterpret_cast<const float2*>(img + 28);

    // precompute (c,s) for the three parameter sets (wave-uniform values)
    float fc[5], fs[5], qc[5], qs[5], kc[5], ks[5];
#pragma unroll
    for (int i = 0; i < 5; ++i) {
        __sincosf(fp[i] * 0.5f, &fs[i], &fc[i]);
        __sincosf(ap[i] * 0.5f, &qs[i], &qc[i]);
        __sincosf(kp[i] * 0.5f, &ks[i], &kc[i]);
    }

    float re[16], im[16];

    // ---- Stage 1: quantum filter on patch 0 ----
    init_state(re, im);
    encode_ry(re, im, p01.x, p01.y, p23.x, p23.y);
    random_layer_cs(re, im, fc, fs);
    const float m0 = measZ<0>(re, im);
    const float m1 = measZ<1>(re, im);
    const float m2 = measZ<2>(re, im);
    const float m3 = measZ<3>(re, im);

    // ---- Stage 2: quantum self-attention on the 4 features ----
    init_state(re, im);
    encode_ry(re, im, m0, m1, m2, m3);
    random_layer_cs(re, im, qc, qs);
    const float at0 = measZ<0>(re, im);
    const float at1 = measZ<1>(re, im);
    const float at2 = measZ<2>(re, im);
    const float at3 = measZ<3>(re, im);

    // ---- Stage 3: quantum kernel scalar (data-independent; trig reused) ----
    init_state(re, im);
    random_layer_cs(re, im, kc, ks);
    random_layer_cs(re, im, kc, ks);
    const float kval = sqrtf(re[0] * re[0] + im[0] * im[0]);

    // ---- Stage 4: linear + log_softmax ----
    float logit[10];
    float mx = -INFINITY;
#pragma unroll
    for (int c = 0; c < 10; ++c) {
        float v = bia[c];
        v += at0 * W[c * 5 + 0];
        v += at1 * W[c * 5 + 1];
        v += at2 * W[c * 5 + 2];
        v += at3 * W[c * 5 + 3];
        v += kval * W[c * 5 + 4];
        logit[c] = v;
        mx = fmaxf(mx, v);
    }
    float sum = 0.0f;
#pragma unroll
    for (int c = 0; c < 10; ++c) sum += __expf(logit[c] - mx);
    const float lse = __logf(sum) + mx;

    float* o = out + (size_t)t * 10;
#pragma unroll
    for (int c = 0; c < 10; ++c) o[c] = logit[c] - lse;
}

extern "C" void kernel_launch(void* const* d_in, const int* in_sizes, int n_in,
                              void* d_out, int out_size, void* d_ws, size_t ws_size,
                              hipStream_t stream) {
    const float* x  = (const float*)d_in[0];
    const float* fp = (const float*)d_in[1];
    const float* ap = (const float*)d_in[2];
    const float* kp = (const float*)d_in[3];
    const float* W  = (const float*)d_in[4];
    const float* b  = (const float*)d_in[5];
    float* out = (float*)d_out;

    const int B = in_sizes[0] / 784;  // 4096
    // block=64: one wave per workgroup -> 64 workgroups spread over 64 CUs,
    // minimizing per-CU serial latency for this latency-bound tiny grid.
    const int block = 64;
    const int grid = (B + block - 1) / block;
    quanv_collapsed_kernel<<<grid, block, 0, stream>>>(x, fp, ap, kp, W, b, out, B);
}